// Round 1
// baseline (397.670 us; speedup 1.0000x reference)
//
#include <hip/hip_runtime.h>
#include <cstdint>

#define A_NUM 9
#define C_NUM 20
#define B_SZ 32
#define HW 784            // 28*28
#define P_NUM (A_NUM*HW)  // 7056
#define NBOX 64
#define CIN 1280
#define HID 128
#define M_IDX 4096

// output layout (flat concat in return order)
#define CONF_OFF 0
#define OFFS_OFF (2*M_IDX)                 // 8192
#define CLS_OFF  (OFFS_OFF + 4*M_IDX)      // 24576
#define IOU_OFF  (CLS_OFF + C_NUM*M_IDX)   // 106496

// ---------------- IoU kernel: one thread per (b,p,n) output ----------------
__global__ __launch_bounds__(256) void iou_kernel(
    const float* __restrict__ grid, const float* __restrict__ anc,
    const float* __restrict__ bboxes, float* __restrict__ out) {
  __shared__ float sb[NBOX * 5];
  int b = blockIdx.y;
  int t = threadIdx.x;
  for (int i = t; i < NBOX * 5; i += 256) sb[i] = bboxes[b * NBOX * 5 + i];
  __syncthreads();
  int p = blockIdx.x * 4 + (t >> 6);
  int n = t & 63;
  int a = p / HW;
  int hw = p - a * HW;
  float cx = grid[(b * HW + hw) * 2 + 0];
  float cy = grid[(b * HW + hw) * 2 + 1];
  float hx = anc[a * 2 + 0] * 0.5f, hy = anc[a * 2 + 1] * 0.5f;
  float x1 = cx - hx, y1 = cy - hy, x2 = cx + hx, y2 = cy + hy;
  float sp = (x2 - x1) * (y2 - y1);
  float bx1 = sb[n * 5 + 0], by1 = sb[n * 5 + 1];
  float bx2 = sb[n * 5 + 2], by2 = sb[n * 5 + 3];
  float s_b = (bx2 - bx1) * (by2 - by1);
  float ix1 = fmaxf(x1, bx1), iy1 = fmaxf(y1, by1);
  float ix2 = fminf(x2, bx2), iy2 = fminf(y2, by2);
  float si = fmaxf(ix2 - ix1, 0.f) * fmaxf(iy2 - iy1, 0.f);
  float su = sp + s_b - si;
  float iou = fmaxf(si / (su + 1e-8f), 0.f);
  bool invalid = (su <= 0.f) | (sp <= 0.f) | (s_b <= 0.f) | (bx1 < 0.f);
  out[((size_t)(b * P_NUM + p)) * 64 + n] = invalid ? 0.f : iou;
}

// ---------------- Layer-1 GEMM: h[b,hw,j] = leaky(sum_c W1[j,c]*F[b,c,hw]+b1[j])
#define BM 64
#define BN 128
#define BK 16
__global__ __launch_bounds__(256) void gemm1_kernel(
    const float* __restrict__ F, const float* __restrict__ W1,
    const float* __restrict__ b1, float* __restrict__ Hws) {
  __shared__ float As[BK][BM];   // F[c, hw] tile
  __shared__ float Bs[BK][BN];   // W1[j, c] tile, stored [k][n]
  int b = blockIdx.z;
  int m0 = blockIdx.x * BM;
  int t = threadIdx.x;
  int tm = (t & 15) * 4;         // 4 hw per thread
  int tn = (t >> 4) * 8;         // 8 j per thread
  float acc[4][8];
#pragma unroll
  for (int i = 0; i < 4; i++)
#pragma unroll
    for (int j = 0; j < 8; j++) acc[i][j] = 0.f;
  const float* Fb = F + (size_t)b * CIN * HW;
  int mq = t & 15, ka = t >> 4;          // A-load: float4 along hw
  int nb = t >> 1, kb = (t & 1) * 8;     // B-load: 8 consecutive c of row nb

  for (int k0 = 0; k0 < CIN; k0 += BK) {
    int gm = m0 + mq * 4;
    const float* src = Fb + (size_t)(k0 + ka) * HW + gm;
    if (gm + 3 < HW) {
      *(float4*)&As[ka][mq * 4] = *(const float4*)src;
    } else {
#pragma unroll
      for (int i = 0; i < 4; i++) As[ka][mq * 4 + i] = (gm + i < HW) ? src[i] : 0.f;
    }
    const float* wsrc = W1 + (size_t)nb * CIN + k0 + kb;
    float4 w0 = *(const float4*)wsrc;
    float4 w1 = *(const float4*)(wsrc + 4);
    Bs[kb + 0][nb] = w0.x; Bs[kb + 1][nb] = w0.y;
    Bs[kb + 2][nb] = w0.z; Bs[kb + 3][nb] = w0.w;
    Bs[kb + 4][nb] = w1.x; Bs[kb + 5][nb] = w1.y;
    Bs[kb + 6][nb] = w1.z; Bs[kb + 7][nb] = w1.w;
    __syncthreads();
#pragma unroll
    for (int k = 0; k < BK; k++) {
      float av[4], bv[8];
      *(float4*)av = *(const float4*)&As[k][tm];
      *(float4*)bv = *(const float4*)&Bs[k][tn];
      *(float4*)(bv + 4) = *(const float4*)&Bs[k][tn + 4];
#pragma unroll
      for (int i = 0; i < 4; i++)
#pragma unroll
        for (int j = 0; j < 8; j++) acc[i][j] = fmaf(av[i], bv[j], acc[i][j]);
    }
    __syncthreads();
  }
#pragma unroll
  for (int i = 0; i < 4; i++) {
    int gm = m0 + tm + i;
    if (gm < HW) {
      float* dst = Hws + ((size_t)(b * HW + gm)) * HID + tn;
      float tmp[8];
#pragma unroll
      for (int j = 0; j < 8; j++) {
        float v = acc[i][j] + b1[tn + j];
        tmp[j] = v > 0.f ? v : 0.01f * v;
      }
      *(float4*)dst = *(float4*)tmp;
      *(float4*)(dst + 4) = *(float4*)(tmp + 4);
    }
  }
}

// ---------------- Gathered layer-2 head: one 64-thread block per index ------
__global__ __launch_bounds__(64) void gather_kernel(
    const int* __restrict__ pos_idx, const int* __restrict__ neg_idx,
    const float* __restrict__ Hws, const float* __restrict__ W2,
    const float* __restrict__ b2, float* __restrict__ out) {
  __shared__ float sh[HID];
  int blk = blockIdx.x;
  int l = threadIdx.x;  // 0..63
  bool pos = blk < M_IDX;
  int idx = pos ? pos_idx[blk] : neg_idx[blk - M_IDX];
  int b = idx / P_NUM;
  int r = idx - b * P_NUM;
  int a = r / HW;
  int hw = r - a * HW;
  const float* hrow = Hws + ((size_t)(b * HW + hw)) * HID;
  float v0 = hrow[2 * l], v1 = hrow[2 * l + 1];
  sh[2 * l] = v0; sh[2 * l + 1] = v1;
  __syncthreads();
  if (pos) {
    if (l < 25) {
      int o = (l < 5) ? (a * 5 + l) : (5 * A_NUM + (l - 5));
      const float* w = W2 + o * HID;
      float dot = b2[o];
#pragma unroll 8
      for (int k = 0; k < HID; k++) dot = fmaf(w[k], sh[k], dot);
      if (l == 0) {
        out[CONF_OFF + blk] = 1.f / (1.f + expf(-dot));
      } else if (l < 3) {
        out[OFFS_OFF + blk * 4 + (l - 1)] = 1.f / (1.f + expf(-dot)) - 0.5f;
      } else if (l < 5) {
        out[OFFS_OFF + blk * 4 + (l - 1)] = dot;
      } else {
        out[CLS_OFF + blk * C_NUM + (l - 5)] = dot;
      }
    }
  } else {
    int o = a * 5;
    const float* w = W2 + o * HID;
    float part = fmaf(w[2 * l], v0, w[2 * l + 1] * v1);
#pragma unroll
    for (int off = 32; off > 0; off >>= 1) part += __shfl_down(part, off);
    if (l == 0) out[CONF_OFF + blk] = 1.f / (1.f + expf(-(b2[o] + part)));
  }
}

extern "C" void kernel_launch(void* const* d_in, const int* in_sizes, int n_in,
                              void* d_out, int out_size, void* d_ws, size_t ws_size,
                              hipStream_t stream) {
  const float* features = (const float*)d_in[0];
  const float* grid     = (const float*)d_in[1];
  const float* anc      = (const float*)d_in[2];
  const float* bboxes   = (const float*)d_in[3];
  const int*   pos_idx  = (const int*)d_in[4];
  const int*   neg_idx  = (const int*)d_in[5];
  const float* W1       = (const float*)d_in[6];
  const float* b1       = (const float*)d_in[7];
  const float* W2       = (const float*)d_in[8];
  const float* b2       = (const float*)d_in[9];
  float* out = (float*)d_out;
  float* Hws = (float*)d_ws;  // (B, HW, HID) fp32 = 12.85 MB

  hipLaunchKernelGGL(gemm1_kernel, dim3((HW + BM - 1) / BM, 1, B_SZ), dim3(256),
                     0, stream, features, W1, b1, Hws);
  hipLaunchKernelGGL(iou_kernel, dim3(P_NUM / 4, B_SZ), dim3(256),
                     0, stream, grid, anc, bboxes, out + IOU_OFF);
  hipLaunchKernelGGL(gather_kernel, dim3(2 * M_IDX), dim3(64),
                     0, stream, pos_idx, neg_idx, Hws, W2, b2, out);
}

// Round 2
// 289.481 us; speedup vs baseline: 1.3737x; 1.3737x over previous
//
#include <hip/hip_runtime.h>
#include <cstdint>

#define A_NUM 9
#define C_NUM 20
#define B_SZ 32
#define HW 784            // 28*28
#define P_NUM (A_NUM*HW)  // 7056
#define NBOX 64
#define CIN 1280
#define HID 128
#define M_IDX 4096
#define NK 40             // 1280 / 32
#define ASTR 40           // padded A LDS row stride in bf16 elems (80 B)

// output layout (flat concat in return order)
#define CONF_OFF 0
#define OFFS_OFF (2*M_IDX)                 // 8192
#define CLS_OFF  (OFFS_OFF + 4*M_IDX)      // 24576
#define IOU_OFF  (CLS_OFF + C_NUM*M_IDX)   // 106496

typedef short bf16x8 __attribute__((ext_vector_type(8)));
typedef float f32x4  __attribute__((ext_vector_type(4)));

// round-half-up fp32->bf16, packed pair into one dword
__device__ __forceinline__ unsigned pack_bf16(float lo, float hi) {
  unsigned a = __builtin_bit_cast(unsigned, lo);
  unsigned b = __builtin_bit_cast(unsigned, hi);
  return ((a + 0x8000u) >> 16) | ((b + 0x8000u) & 0xffff0000u);
}

// ---------------- W1 prep: fp32 [n][c] -> bf16 swizzled [ks][n][k=32] -------
__global__ __launch_bounds__(256) void prep_w1(const float* __restrict__ W1,
                                               unsigned* __restrict__ W1sw) {
  int id = blockIdx.x * 256 + threadIdx.x;  // 20480 threads, 8 elems each
  int kk = (id & 3) * 8;
  int n  = (id >> 2) & 127;
  int ks = id >> 9;                         // 0..39
  const float* src = W1 + n * CIN + ks * 32 + kk;
  float4 x = *(const float4*)src;
  float4 y = *(const float4*)(src + 4);
  uint4 p;
  p.x = pack_bf16(x.x, x.y);
  p.y = pack_bf16(x.z, x.w);
  p.z = pack_bf16(y.x, y.y);
  p.w = pack_bf16(y.z, y.w);
  // dword index: (ks*4096 + n*32 + kk) bf16 elems / 2
  *(uint4*)&W1sw[(ks * 4096 + n * 32 + kk) >> 1] = p;
}

// ---------------- Layer-1 GEMM via MFMA -------------------------------------
// h[b,m,n] = leaky(sum_c F[b,c,m] * W1[n,c] + b1[n]),  m=hw, n=j
// Block: 128(m) x 128(n), 256 threads = 4 waves (2x2), wave = 64x64 (4x4 MFMA tiles)
__global__ __launch_bounds__(256) void gemm1_mfma(
    const float* __restrict__ F, const unsigned short* __restrict__ W1sw,
    const float* __restrict__ b1, float* __restrict__ Hws) {
  __shared__ unsigned short Asm[2][128 * ASTR];  // A[m][k], padded stride 40
  __shared__ unsigned short Bsm[2][128 * 32];    // B[n][k], dense

  const int b = blockIdx.y;
  const int m0 = blockIdx.x * 128;
  const int t = threadIdx.x;
  const int wave = t >> 6, lane = t & 63;
  const int wm = wave >> 1, wn = wave & 1;
  const int quad = lane >> 4, lo = lane & 15;

  // A staging assignment: thread covers (m = t&127, k = (t>>7)*16 .. +15)
  const int sm = t & 127;
  const int kh = t >> 7;
  const int gm = m0 + sm;
  const bool mval = gm < HW;
  const float* Fb = F + (size_t)b * CIN * HW + (mval ? gm : 0);

  f32x4 acc[4][4];
#pragma unroll
  for (int i = 0; i < 4; i++)
#pragma unroll
    for (int j = 0; j < 4; j++) acc[i][j] = (f32x4){0.f, 0.f, 0.f, 0.f};

  float va[16];
  uint4 vb0, vb1;

  auto loadG = [&](int ks) {
    const int k0 = ks * 32 + kh * 16;
#pragma unroll
    for (int i = 0; i < 16; i++) va[i] = Fb[(size_t)(k0 + i) * HW];
    const unsigned short* g = W1sw + ks * 4096 + t * 16;
    vb0 = *(const uint4*)g;
    vb1 = *(const uint4*)(g + 8);
  };

  auto stage = [&](int buf) {
    uint4 p0, p1;
    if (mval) {
      p0.x = pack_bf16(va[0], va[1]);   p0.y = pack_bf16(va[2], va[3]);
      p0.z = pack_bf16(va[4], va[5]);   p0.w = pack_bf16(va[6], va[7]);
      p1.x = pack_bf16(va[8], va[9]);   p1.y = pack_bf16(va[10], va[11]);
      p1.z = pack_bf16(va[12], va[13]); p1.w = pack_bf16(va[14], va[15]);
    } else {
      p0 = (uint4){0, 0, 0, 0}; p1 = p0;
    }
    *(uint4*)&Asm[buf][sm * ASTR + kh * 16] = p0;
    *(uint4*)&Asm[buf][sm * ASTR + kh * 16 + 8] = p1;
    *(uint4*)&Bsm[buf][t * 16] = vb0;
    *(uint4*)&Bsm[buf][t * 16 + 8] = vb1;
  };

  auto compute = [&](int buf) {
    const unsigned short* Ab = &Asm[buf][(wm * 64 + lo) * ASTR + quad * 8];
    const unsigned short* Bb = &Bsm[buf][(wn * 64 + lo) * 32 + quad * 8];
    bf16x8 af[4], bfr[4];
#pragma unroll
    for (int i = 0; i < 4; i++) af[i] = *(const bf16x8*)(Ab + i * 16 * ASTR);
#pragma unroll
    for (int j = 0; j < 4; j++) bfr[j] = *(const bf16x8*)(Bb + j * 16 * 32);
#pragma unroll
    for (int i = 0; i < 4; i++)
#pragma unroll
      for (int j = 0; j < 4; j++)
        acc[i][j] = __builtin_amdgcn_mfma_f32_16x16x32_bf16(af[i], bfr[j],
                                                            acc[i][j], 0, 0, 0);
  };

  loadG(0);
  stage(0);
  __syncthreads();
  for (int ks = 0; ks < NK; ks++) {
    const int cur = ks & 1;
    if (ks + 1 < NK) loadG(ks + 1);   // prefetch next tile into regs
    compute(cur);                      // MFMA from current buffer
    if (ks + 1 < NK) stage(cur ^ 1);   // convert + write next buffer
    __syncthreads();
  }

  // epilogue: bias + leaky relu, store fp32 Hws[b][m][n]
#pragma unroll
  for (int i = 0; i < 4; i++) {
    const int mbase = m0 + wm * 64 + i * 16 + quad * 4;
#pragma unroll
    for (int j = 0; j < 4; j++) {
      const int n = wn * 64 + j * 16 + lo;
      const float bias = b1[n];
#pragma unroll
      for (int r = 0; r < 4; r++) {
        const int mm = mbase + r;
        if (mm < HW) {
          float v = acc[i][j][r] + bias;
          Hws[((size_t)(b * HW + mm)) * HID + n] = v > 0.f ? v : 0.01f * v;
        }
      }
    }
  }
}

// ---------------- IoU kernel: one thread per (b,p,n) output ----------------
__global__ __launch_bounds__(256) void iou_kernel(
    const float* __restrict__ grid, const float* __restrict__ anc,
    const float* __restrict__ bboxes, float* __restrict__ out) {
  __shared__ float sb[NBOX * 5];
  int b = blockIdx.y;
  int t = threadIdx.x;
  for (int i = t; i < NBOX * 5; i += 256) sb[i] = bboxes[b * NBOX * 5 + i];
  __syncthreads();
  int p = blockIdx.x * 4 + (t >> 6);
  int n = t & 63;
  int a = p / HW;
  int hw = p - a * HW;
  float cx = grid[(b * HW + hw) * 2 + 0];
  float cy = grid[(b * HW + hw) * 2 + 1];
  float hx = anc[a * 2 + 0] * 0.5f, hy = anc[a * 2 + 1] * 0.5f;
  float x1 = cx - hx, y1 = cy - hy, x2 = cx + hx, y2 = cy + hy;
  float sp = (x2 - x1) * (y2 - y1);
  float bx1 = sb[n * 5 + 0], by1 = sb[n * 5 + 1];
  float bx2 = sb[n * 5 + 2], by2 = sb[n * 5 + 3];
  float s_b = (bx2 - bx1) * (by2 - by1);
  float ix1 = fmaxf(x1, bx1), iy1 = fmaxf(y1, by1);
  float ix2 = fminf(x2, bx2), iy2 = fminf(y2, by2);
  float si = fmaxf(ix2 - ix1, 0.f) * fmaxf(iy2 - iy1, 0.f);
  float su = sp + s_b - si;
  float iou = fmaxf(si / (su + 1e-8f), 0.f);
  bool invalid = (su <= 0.f) | (sp <= 0.f) | (s_b <= 0.f) | (bx1 < 0.f);
  out[((size_t)(b * P_NUM + p)) * 64 + n] = invalid ? 0.f : iou;
}

// ---------------- Gathered layer-2 head: one 64-thread block per index ------
__global__ __launch_bounds__(64) void gather_kernel(
    const int* __restrict__ pos_idx, const int* __restrict__ neg_idx,
    const float* __restrict__ Hws, const float* __restrict__ W2,
    const float* __restrict__ b2, float* __restrict__ out) {
  __shared__ float sh[HID];
  int blk = blockIdx.x;
  int l = threadIdx.x;  // 0..63
  bool pos = blk < M_IDX;
  int idx = pos ? pos_idx[blk] : neg_idx[blk - M_IDX];
  int b = idx / P_NUM;
  int r = idx - b * P_NUM;
  int a = r / HW;
  int hw = r - a * HW;
  const float* hrow = Hws + ((size_t)(b * HW + hw)) * HID;
  float v0 = hrow[2 * l], v1 = hrow[2 * l + 1];
  sh[2 * l] = v0; sh[2 * l + 1] = v1;
  __syncthreads();
  if (pos) {
    if (l < 25) {
      int o = (l < 5) ? (a * 5 + l) : (5 * A_NUM + (l - 5));
      const float* w = W2 + o * HID;
      float dot = b2[o];
#pragma unroll 8
      for (int k = 0; k < HID; k++) dot = fmaf(w[k], sh[k], dot);
      if (l == 0) {
        out[CONF_OFF + blk] = 1.f / (1.f + expf(-dot));
      } else if (l < 3) {
        out[OFFS_OFF + blk * 4 + (l - 1)] = 1.f / (1.f + expf(-dot)) - 0.5f;
      } else if (l < 5) {
        out[OFFS_OFF + blk * 4 + (l - 1)] = dot;
      } else {
        out[CLS_OFF + blk * C_NUM + (l - 5)] = dot;
      }
    }
  } else {
    int o = a * 5;
    const float* w = W2 + o * HID;
    float part = fmaf(w[2 * l], v0, w[2 * l + 1] * v1);
#pragma unroll
    for (int off = 32; off > 0; off >>= 1) part += __shfl_down(part, off);
    if (l == 0) out[CONF_OFF + blk] = 1.f / (1.f + expf(-(b2[o] + part)));
  }
}

extern "C" void kernel_launch(void* const* d_in, const int* in_sizes, int n_in,
                              void* d_out, int out_size, void* d_ws, size_t ws_size,
                              hipStream_t stream) {
  const float* features = (const float*)d_in[0];
  const float* grid     = (const float*)d_in[1];
  const float* anc      = (const float*)d_in[2];
  const float* bboxes   = (const float*)d_in[3];
  const int*   pos_idx  = (const int*)d_in[4];
  const int*   neg_idx  = (const int*)d_in[5];
  const float* W1       = (const float*)d_in[6];
  const float* b1       = (const float*)d_in[7];
  const float* W2       = (const float*)d_in[8];
  const float* b2       = (const float*)d_in[9];
  float* out = (float*)d_out;

  // workspace: W1sw (bf16 swizzled, 327680 B) then Hws (B*HW*HID fp32)
  unsigned* W1sw = (unsigned*)d_ws;
  float* Hws = (float*)((char*)d_ws + 327680);

  hipLaunchKernelGGL(prep_w1, dim3(80), dim3(256), 0, stream, W1, W1sw);
  hipLaunchKernelGGL(gemm1_mfma, dim3(7, B_SZ), dim3(256), 0, stream,
                     features, (const unsigned short*)W1sw, b1, Hws);
  hipLaunchKernelGGL(iou_kernel, dim3(P_NUM / 4, B_SZ), dim3(256),
                     0, stream, grid, anc, bboxes, out + IOU_OFF);
  hipLaunchKernelGGL(gather_kernel, dim3(2 * M_IDX), dim3(64),
                     0, stream, pos_idx, neg_idx, Hws, W2, b2, out);
}

// Round 3
// 287.709 us; speedup vs baseline: 1.3822x; 1.0062x over previous
//
#include <hip/hip_runtime.h>
#include <cstdint>

#define A_NUM 9
#define C_NUM 20
#define B_SZ 32
#define HW 784            // 28*28
#define P_NUM (A_NUM*HW)  // 7056
#define NBOX 64
#define CIN 1280
#define HID 128
#define M_IDX 4096
#define KSPLIT 4
#define KS_PER 10         // 40 k-steps / 4 splits
#define ASTR 40           // padded A LDS row stride in bf16 elems (80 B)
#define PSTR ((size_t)B_SZ * HW * HID)   // floats between K-partials

// output layout (flat concat in return order)
#define CONF_OFF 0
#define OFFS_OFF (2*M_IDX)                 // 8192
#define CLS_OFF  (OFFS_OFF + 4*M_IDX)      // 24576
#define IOU_OFF  (CLS_OFF + C_NUM*M_IDX)   // 106496

typedef short bf16x8 __attribute__((ext_vector_type(8)));
typedef float f32x4  __attribute__((ext_vector_type(4)));

// round-half-up fp32->bf16, packed pair into one dword
__device__ __forceinline__ unsigned pack_bf16(float lo, float hi) {
  unsigned a = __builtin_bit_cast(unsigned, lo);
  unsigned b = __builtin_bit_cast(unsigned, hi);
  return ((a + 0x8000u) >> 16) | ((b + 0x8000u) & 0xffff0000u);
}

// ---- W1 prep: fp32 [n][c] -> bf16 in MFMA B-fragment order ----------------
// layout: [ks(40)][ntile(8)][lane(64)][k8], lane=(quad,lo): n=ntile*16+lo,
// k = ks*32 + quad*8 + j.  One wave's frag load = base + lane*16B, coalesced.
__global__ __launch_bounds__(256) void prep_w1(const float* __restrict__ W1,
                                               uint4* __restrict__ W1f) {
  int id = blockIdx.x * 256 + threadIdx.x;  // 20480 threads, 8 bf16 each
  int lane = id & 63;
  int ntile = (id >> 6) & 7;
  int ks = id >> 9;                         // 0..39
  int lo = lane & 15, quad = lane >> 4;
  int n = ntile * 16 + lo;
  int k0 = ks * 32 + quad * 8;
  const float* src = W1 + n * CIN + k0;
  float4 x = *(const float4*)src;
  float4 y = *(const float4*)(src + 4);
  uint4 p;
  p.x = pack_bf16(x.x, x.y);
  p.y = pack_bf16(x.z, x.w);
  p.z = pack_bf16(y.x, y.y);
  p.w = pack_bf16(y.z, y.w);
  W1f[id] = p;
}

// ---- Layer-1 GEMM via MFMA, K-split partials -------------------------------
// Part[z][b][m][n] = sum_{c in z-range} F[b,c,m] * W1[n,c]
// Block: 64(m) x 128(n), 256 thr = 4 waves; wave w covers n in [w*32,w*32+32).
__global__ __launch_bounds__(256) void gemm1_mfma(
    const float* __restrict__ F, const unsigned short* __restrict__ W1f,
    float* __restrict__ Part) {
  __shared__ unsigned short Asm[2][64 * ASTR];  // A[m][k] bf16, padded

  const int b = blockIdx.y;
  const int z = blockIdx.z;
  const int m0 = blockIdx.x * 64;
  const int t = threadIdx.x;
  const int wave = t >> 6, lane = t & 63;
  const int quad = lane >> 4, lo = lane & 15;
  const int ksbase = z * KS_PER;

  // A staging: thread covers (m = t&63, k-byte kh*8 .. +7)
  const int sm = t & 63;
  const int kh = t >> 6;
  const int gm = m0 + sm;
  const bool mval = gm < HW;
  const float* Fb = F + (size_t)b * CIN * HW + (mval ? gm : 0);

  f32x4 acc[4][2];
#pragma unroll
  for (int i = 0; i < 4; i++)
#pragma unroll
    for (int j = 0; j < 2; j++) acc[i][j] = (f32x4){0.f, 0.f, 0.f, 0.f};

  float va[8];
  uint4 vb[2][2];  // [buf][j]

  auto loadA = [&](int kk) {
    const int k0 = (ksbase + kk) * 32 + kh * 8;
#pragma unroll
    for (int i = 0; i < 8; i++) va[i] = Fb[(size_t)(k0 + i) * HW];
  };
  auto loadB = [&](int kk, uint4* dst) {
    const unsigned short* g =
        W1f + (size_t)(((ksbase + kk) * 8 + wave * 2) * 64 + lane) * 8;
    dst[0] = *(const uint4*)g;
    dst[1] = *(const uint4*)(g + 512);  // next ntile
  };
  auto stageA = [&](int buf) {
    uint4 p;
    if (mval) {
      p.x = pack_bf16(va[0], va[1]);
      p.y = pack_bf16(va[2], va[3]);
      p.z = pack_bf16(va[4], va[5]);
      p.w = pack_bf16(va[6], va[7]);
    } else {
      p = (uint4){0, 0, 0, 0};
    }
    *(uint4*)&Asm[buf][sm * ASTR + kh * 8] = p;
  };
  auto compute = [&](int buf, uint4* bv) {
    const unsigned short* Ab = &Asm[buf][lo * ASTR + quad * 8];
    bf16x8 af[4];
#pragma unroll
    for (int i = 0; i < 4; i++) af[i] = *(const bf16x8*)(Ab + i * 16 * ASTR);
    bf16x8 b0 = __builtin_bit_cast(bf16x8, bv[0]);
    bf16x8 b1 = __builtin_bit_cast(bf16x8, bv[1]);
#pragma unroll
    for (int i = 0; i < 4; i++) {
      acc[i][0] = __builtin_amdgcn_mfma_f32_16x16x32_bf16(af[i], b0, acc[i][0], 0, 0, 0);
      acc[i][1] = __builtin_amdgcn_mfma_f32_16x16x32_bf16(af[i], b1, acc[i][1], 0, 0, 0);
    }
  };

  loadA(0);
  loadB(0, vb[0]);
  stageA(0);
  __syncthreads();
  for (int kk = 0; kk < KS_PER; kk++) {
    const int cur = kk & 1;
    if (kk + 1 < KS_PER) {
      loadA(kk + 1);
      loadB(kk + 1, vb[cur ^ 1]);
    }
    compute(cur, vb[cur]);
    if (kk + 1 < KS_PER) stageA(cur ^ 1);
    __syncthreads();
  }

  // store fp32 partial (no bias/activation here)
  float* Pz = Part + ((size_t)(z * B_SZ + b) * HW) * HID;
#pragma unroll
  for (int i = 0; i < 4; i++) {
    const int mbase = m0 + i * 16 + quad * 4;
#pragma unroll
    for (int j = 0; j < 2; j++) {
      const int n = wave * 32 + j * 16 + lo;
#pragma unroll
      for (int r = 0; r < 4; r++) {
        const int mm = mbase + r;
        if (mm < HW) Pz[(size_t)mm * HID + n] = acc[i][j][r];
      }
    }
  }
}

// ---------------- IoU kernel: one thread per (b,p,n) output ----------------
__global__ __launch_bounds__(256) void iou_kernel(
    const float* __restrict__ grid, const float* __restrict__ anc,
    const float* __restrict__ bboxes, float* __restrict__ out) {
  __shared__ float sb[NBOX * 5];
  int b = blockIdx.y;
  int t = threadIdx.x;
  for (int i = t; i < NBOX * 5; i += 256) sb[i] = bboxes[b * NBOX * 5 + i];
  __syncthreads();
  int p = blockIdx.x * 4 + (t >> 6);
  int n = t & 63;
  int a = p / HW;
  int hw = p - a * HW;
  float cx = grid[(b * HW + hw) * 2 + 0];
  float cy = grid[(b * HW + hw) * 2 + 1];
  float hx = anc[a * 2 + 0] * 0.5f, hy = anc[a * 2 + 1] * 0.5f;
  float x1 = cx - hx, y1 = cy - hy, x2 = cx + hx, y2 = cy + hy;
  float sp = (x2 - x1) * (y2 - y1);
  float bx1 = sb[n * 5 + 0], by1 = sb[n * 5 + 1];
  float bx2 = sb[n * 5 + 2], by2 = sb[n * 5 + 3];
  float s_b = (bx2 - bx1) * (by2 - by1);
  float ix1 = fmaxf(x1, bx1), iy1 = fmaxf(y1, by1);
  float ix2 = fminf(x2, bx2), iy2 = fminf(y2, by2);
  float si = fmaxf(ix2 - ix1, 0.f) * fmaxf(iy2 - iy1, 0.f);
  float su = sp + s_b - si;
  float iou = fmaxf(si / (su + 1e-8f), 0.f);
  bool invalid = (su <= 0.f) | (sp <= 0.f) | (s_b <= 0.f) | (bx1 < 0.f);
  out[((size_t)(b * P_NUM + p)) * 64 + n] = invalid ? 0.f : iou;
}

// ---- Gathered layer-2 head: sums K-partials, applies bias+leaky, W2 dot ----
__global__ __launch_bounds__(64) void gather_kernel(
    const int* __restrict__ pos_idx, const int* __restrict__ neg_idx,
    const float* __restrict__ Part, const float* __restrict__ b1,
    const float* __restrict__ W2, const float* __restrict__ b2,
    float* __restrict__ out) {
  __shared__ float sh[HID];
  int blk = blockIdx.x;
  int l = threadIdx.x;  // 0..63
  bool pos = blk < M_IDX;
  int idx = pos ? pos_idx[blk] : neg_idx[blk - M_IDX];
  int b = idx / P_NUM;
  int r = idx - b * P_NUM;
  int a = r / HW;
  int hw = r - a * HW;
  const float2* row = (const float2*)(Part + ((size_t)(b * HW + hw)) * HID) + l;
  float2 s0 = row[0];
  float2 s1 = row[PSTR / 2];
  float2 s2 = row[2 * (PSTR / 2)];
  float2 s3 = row[3 * (PSTR / 2)];
  float v0 = s0.x + s1.x + s2.x + s3.x + b1[2 * l];
  float v1 = s0.y + s1.y + s2.y + s3.y + b1[2 * l + 1];
  v0 = v0 > 0.f ? v0 : 0.01f * v0;
  v1 = v1 > 0.f ? v1 : 0.01f * v1;
  sh[2 * l] = v0; sh[2 * l + 1] = v1;
  __syncthreads();
  if (pos) {
    if (l < 25) {
      int o = (l < 5) ? (a * 5 + l) : (5 * A_NUM + (l - 5));
      const float* w = W2 + o * HID;
      float dot = b2[o];
#pragma unroll 8
      for (int k = 0; k < HID; k++) dot = fmaf(w[k], sh[k], dot);
      if (l == 0) {
        out[CONF_OFF + blk] = 1.f / (1.f + expf(-dot));
      } else if (l < 3) {
        out[OFFS_OFF + blk * 4 + (l - 1)] = 1.f / (1.f + expf(-dot)) - 0.5f;
      } else if (l < 5) {
        out[OFFS_OFF + blk * 4 + (l - 1)] = dot;
      } else {
        out[CLS_OFF + blk * C_NUM + (l - 5)] = dot;
      }
    }
  } else {
    int o = a * 5;
    const float* w = W2 + o * HID;
    float part = fmaf(w[2 * l], v0, w[2 * l + 1] * v1);
#pragma unroll
    for (int off = 32; off > 0; off >>= 1) part += __shfl_down(part, off);
    if (l == 0) out[CONF_OFF + blk] = 1.f / (1.f + expf(-(b2[o] + part)));
  }
}

extern "C" void kernel_launch(void* const* d_in, const int* in_sizes, int n_in,
                              void* d_out, int out_size, void* d_ws, size_t ws_size,
                              hipStream_t stream) {
  const float* features = (const float*)d_in[0];
  const float* grid     = (const float*)d_in[1];
  const float* anc      = (const float*)d_in[2];
  const float* bboxes   = (const float*)d_in[3];
  const int*   pos_idx  = (const int*)d_in[4];
  const int*   neg_idx  = (const int*)d_in[5];
  const float* W1       = (const float*)d_in[6];
  const float* b1       = (const float*)d_in[7];
  const float* W2       = (const float*)d_in[8];
  const float* b2       = (const float*)d_in[9];
  float* out = (float*)d_out;

  // ws: W1f (bf16 frag-order, 327680 B) then Part (KSPLIT * B*HW*HID fp32)
  uint4* W1f = (uint4*)d_ws;
  float* Part = (float*)((char*)d_ws + 327680);

  hipLaunchKernelGGL(prep_w1, dim3(80), dim3(256), 0, stream, W1, W1f);
  hipLaunchKernelGGL(gemm1_mfma, dim3(13, B_SZ, KSPLIT), dim3(256), 0, stream,
                     features, (const unsigned short*)W1f, Part);
  hipLaunchKernelGGL(iou_kernel, dim3(P_NUM / 4, B_SZ), dim3(256),
                     0, stream, grid, anc, bboxes, out + IOU_OFF);
  hipLaunchKernelGGL(gather_kernel, dim3(2 * M_IDX), dim3(64),
                     0, stream, pos_idx, neg_idx, Part, b1, W2, b2, out);
}

// Round 4
// 262.502 us; speedup vs baseline: 1.5149x; 1.0960x over previous
//
#include <hip/hip_runtime.h>
#include <cstdint>

#define A_NUM 9
#define C_NUM 20
#define B_SZ 32
#define HW 784            // 28*28
#define P_NUM (A_NUM*HW)  // 7056
#define NBOX 64
#define CIN 1280
#define HID 128
#define M_IDX 4096
#define KSPLIT 4
#define KS_PER 10         // 40 k-steps / 4 splits
#define ASTR 40           // padded A LDS row stride in bf16 elems (80 B)
#define PSTR ((size_t)B_SZ * HW * HID)   // floats between K-partials
#define IOU_PB 64         // p-rows per iou block

// output layout (flat concat in return order)
#define CONF_OFF 0
#define OFFS_OFF (2*M_IDX)                 // 8192
#define CLS_OFF  (OFFS_OFF + 4*M_IDX)      // 24576
#define IOU_OFF  (CLS_OFF + C_NUM*M_IDX)   // 106496

typedef short bf16x8 __attribute__((ext_vector_type(8)));
typedef float f32x4  __attribute__((ext_vector_type(4)));

// round-half-up fp32->bf16, packed pair into one dword
__device__ __forceinline__ unsigned pack_bf16(float lo, float hi) {
  unsigned a = __builtin_bit_cast(unsigned, lo);
  unsigned b = __builtin_bit_cast(unsigned, hi);
  return ((a + 0x8000u) >> 16) | ((b + 0x8000u) & 0xffff0000u);
}

// ---- W1 prep: fp32 [n][c] -> bf16 in MFMA B-fragment order ----------------
// layout: [ks(40)][ntile(8)][lane(64)][k8], lane=(quad,lo): n=ntile*16+lo,
// k = ks*32 + quad*8 + j.  One wave's frag load = base + lane*16B, coalesced.
__global__ __launch_bounds__(256) void prep_w1(const float* __restrict__ W1,
                                               uint4* __restrict__ W1f) {
  int id = blockIdx.x * 256 + threadIdx.x;  // 20480 threads, 8 bf16 each
  int lane = id & 63;
  int ntile = (id >> 6) & 7;
  int ks = id >> 9;                         // 0..39
  int lo = lane & 15, quad = lane >> 4;
  int n = ntile * 16 + lo;
  int k0 = ks * 32 + quad * 8;
  const float* src = W1 + n * CIN + k0;
  float4 x = *(const float4*)src;
  float4 y = *(const float4*)(src + 4);
  uint4 p;
  p.x = pack_bf16(x.x, x.y);
  p.y = pack_bf16(x.z, x.w);
  p.z = pack_bf16(y.x, y.y);
  p.w = pack_bf16(y.z, y.w);
  W1f[id] = p;
}

// ---- Layer-1 GEMM via MFMA, K-split partials (unchanged from r3) -----------
// Part[z][b][m][n] = sum_{c in z-range} F[b,c,m] * W1[n,c]
__global__ __launch_bounds__(256) void gemm1_mfma(
    const float* __restrict__ F, const unsigned short* __restrict__ W1f,
    float* __restrict__ Part) {
  __shared__ unsigned short Asm[2][64 * ASTR];  // A[m][k] bf16, padded

  const int b = blockIdx.y;
  const int z = blockIdx.z;
  const int m0 = blockIdx.x * 64;
  const int t = threadIdx.x;
  const int wave = t >> 6, lane = t & 63;
  const int quad = lane >> 4, lo = lane & 15;
  const int ksbase = z * KS_PER;

  const int sm = t & 63;
  const int kh = t >> 6;
  const int gm = m0 + sm;
  const bool mval = gm < HW;
  const float* Fb = F + (size_t)b * CIN * HW + (mval ? gm : 0);

  f32x4 acc[4][2];
#pragma unroll
  for (int i = 0; i < 4; i++)
#pragma unroll
    for (int j = 0; j < 2; j++) acc[i][j] = (f32x4){0.f, 0.f, 0.f, 0.f};

  float va[8];
  uint4 vb[2][2];  // [buf][j]

  auto loadA = [&](int kk) {
    const int k0 = (ksbase + kk) * 32 + kh * 8;
#pragma unroll
    for (int i = 0; i < 8; i++) va[i] = Fb[(size_t)(k0 + i) * HW];
  };
  auto loadB = [&](int kk, uint4* dst) {
    const unsigned short* g =
        W1f + (size_t)(((ksbase + kk) * 8 + wave * 2) * 64 + lane) * 8;
    dst[0] = *(const uint4*)g;
    dst[1] = *(const uint4*)(g + 512);  // next ntile
  };
  auto stageA = [&](int buf) {
    uint4 p;
    if (mval) {
      p.x = pack_bf16(va[0], va[1]);
      p.y = pack_bf16(va[2], va[3]);
      p.z = pack_bf16(va[4], va[5]);
      p.w = pack_bf16(va[6], va[7]);
    } else {
      p = (uint4){0, 0, 0, 0};
    }
    *(uint4*)&Asm[buf][sm * ASTR + kh * 8] = p;
  };
  auto compute = [&](int buf, uint4* bv) {
    const unsigned short* Ab = &Asm[buf][lo * ASTR + quad * 8];
    bf16x8 af[4];
#pragma unroll
    for (int i = 0; i < 4; i++) af[i] = *(const bf16x8*)(Ab + i * 16 * ASTR);
    bf16x8 b0 = __builtin_bit_cast(bf16x8, bv[0]);
    bf16x8 b1 = __builtin_bit_cast(bf16x8, bv[1]);
#pragma unroll
    for (int i = 0; i < 4; i++) {
      acc[i][0] = __builtin_amdgcn_mfma_f32_16x16x32_bf16(af[i], b0, acc[i][0], 0, 0, 0);
      acc[i][1] = __builtin_amdgcn_mfma_f32_16x16x32_bf16(af[i], b1, acc[i][1], 0, 0, 0);
    }
  };

  loadA(0);
  loadB(0, vb[0]);
  stageA(0);
  __syncthreads();
  for (int kk = 0; kk < KS_PER; kk++) {
    const int cur = kk & 1;
    if (kk + 1 < KS_PER) {
      loadA(kk + 1);
      loadB(kk + 1, vb[cur ^ 1]);
    }
    compute(cur, vb[cur]);
    if (kk + 1 < KS_PER) stageA(cur ^ 1);
    __syncthreads();
  }

  float* Pz = Part + ((size_t)(z * B_SZ + b) * HW) * HID;
#pragma unroll
  for (int i = 0; i < 4; i++) {
    const int mbase = m0 + i * 16 + quad * 4;
#pragma unroll
    for (int j = 0; j < 2; j++) {
      const int n = wave * 32 + j * 16 + lo;
#pragma unroll
      for (int r = 0; r < 4; r++) {
        const int mm = mbase + r;
        if (mm < HW) Pz[(size_t)mm * HID + n] = acc[i][j][r];
      }
    }
  }
}

// ---- IoU: 64 p-rows x 64 boxes per block, 16 outputs/thread ---------------
__global__ __launch_bounds__(256) void iou_kernel(
    const float* __restrict__ grid, const float* __restrict__ anc,
    const float* __restrict__ bboxes, float* __restrict__ out) {
  __shared__ float sb[NBOX * 5];
  __shared__ float4 sp4[IOU_PB];
  const int b = blockIdx.y;
  const int p0 = blockIdx.x * IOU_PB;
  const int t = threadIdx.x;
  for (int i = t; i < NBOX * 5; i += 256) sb[i] = bboxes[b * NBOX * 5 + i];
  if (t < IOU_PB) {
    int p = p0 + t;
    float x1 = 0.f, y1 = 0.f, x2 = 0.f, y2 = 0.f;
    if (p < P_NUM) {
      int a = p / HW, hw = p - a * HW;
      float2 c = ((const float2*)grid)[b * HW + hw];
      float hx = anc[a * 2 + 0] * 0.5f, hy = anc[a * 2 + 1] * 0.5f;
      x1 = c.x - hx; y1 = c.y - hy; x2 = c.x + hx; y2 = c.y + hy;
    }
    sp4[t] = make_float4(x1, y1, x2, y2);
  }
  __syncthreads();
  const int nl = (t & 15) * 4;   // 4 consecutive boxes per thread
  const int pi = t >> 4;         // 16 p-slots, x4 via ip
#pragma unroll
  for (int ip = 0; ip < 4; ip++) {
    const int pl = pi + 16 * ip;
    const int p = p0 + pl;
    const float4 pb = sp4[pl];
    const float spA = (pb.z - pb.x) * (pb.w - pb.y);
    float4 res;
#pragma unroll
    for (int jn = 0; jn < 4; jn++) {
      const int n = nl + jn;
      float bx1 = sb[n * 5 + 0], by1 = sb[n * 5 + 1];
      float bx2 = sb[n * 5 + 2], by2 = sb[n * 5 + 3];
      float s_b = (bx2 - bx1) * (by2 - by1);
      float ix1 = fmaxf(pb.x, bx1), iy1 = fmaxf(pb.y, by1);
      float ix2 = fminf(pb.z, bx2), iy2 = fminf(pb.w, by2);
      float si = fmaxf(ix2 - ix1, 0.f) * fmaxf(iy2 - iy1, 0.f);
      float su = spA + s_b - si;
      float iou = fmaxf(si / (su + 1e-8f), 0.f);
      bool invalid = (su <= 0.f) | (spA <= 0.f) | (s_b <= 0.f) | (bx1 < 0.f);
      float v = invalid ? 0.f : iou;
      if (jn == 0) res.x = v; else if (jn == 1) res.y = v;
      else if (jn == 2) res.z = v; else res.w = v;
    }
    if (p < P_NUM)
      *(float4*)&out[((size_t)(b * P_NUM + p)) * 64 + nl] = res;
  }
}

// ---- Gathered layer-2 head: 4 indices per block (one per wave) -------------
__global__ __launch_bounds__(256) void gather_kernel(
    const int* __restrict__ pos_idx, const int* __restrict__ neg_idx,
    const float* __restrict__ Part, const float* __restrict__ b1,
    const float* __restrict__ W2, const float* __restrict__ b2,
    float* __restrict__ out) {
  __shared__ float sh[4][HID];
  const int sub = threadIdx.x >> 6;     // wave id = which index slot
  const int l = threadIdx.x & 63;
  const int blk = blockIdx.x * 4 + sub; // 0..8191
  const bool pos = blk < M_IDX;
  const int idx = pos ? pos_idx[blk] : neg_idx[blk - M_IDX];
  const int b = idx / P_NUM;
  const int r = idx - b * P_NUM;
  const int a = r / HW;
  const int hw = r - a * HW;
  const float2* row = (const float2*)(Part + ((size_t)(b * HW + hw)) * HID) + l;
  float2 s0 = row[0];
  float2 s1 = row[PSTR / 2];
  float2 s2 = row[2 * (PSTR / 2)];
  float2 s3 = row[3 * (PSTR / 2)];
  float v0 = s0.x + s1.x + s2.x + s3.x + b1[2 * l];
  float v1 = s0.y + s1.y + s2.y + s3.y + b1[2 * l + 1];
  v0 = v0 > 0.f ? v0 : 0.01f * v0;
  v1 = v1 > 0.f ? v1 : 0.01f * v1;
  sh[sub][2 * l] = v0; sh[sub][2 * l + 1] = v1;
  __syncthreads();
  if (pos) {
    if (l < 25) {
      int o = (l < 5) ? (a * 5 + l) : (5 * A_NUM + (l - 5));
      const float* w = W2 + o * HID;
      float dot = b2[o];
#pragma unroll 8
      for (int k = 0; k < HID; k++) dot = fmaf(w[k], sh[sub][k], dot);
      if (l == 0) {
        out[CONF_OFF + blk] = 1.f / (1.f + expf(-dot));
      } else if (l < 3) {
        out[OFFS_OFF + blk * 4 + (l - 1)] = 1.f / (1.f + expf(-dot)) - 0.5f;
      } else if (l < 5) {
        out[OFFS_OFF + blk * 4 + (l - 1)] = dot;
      } else {
        out[CLS_OFF + blk * C_NUM + (l - 5)] = dot;
      }
    }
  } else {
    int o = a * 5;
    const float* w = W2 + o * HID;
    float part = fmaf(w[2 * l], v0, w[2 * l + 1] * v1);
#pragma unroll
    for (int off = 32; off > 0; off >>= 1) part += __shfl_down(part, off);
    if (l == 0) out[CONF_OFF + blk] = 1.f / (1.f + expf(-(b2[o] + part)));
  }
}

extern "C" void kernel_launch(void* const* d_in, const int* in_sizes, int n_in,
                              void* d_out, int out_size, void* d_ws, size_t ws_size,
                              hipStream_t stream) {
  const float* features = (const float*)d_in[0];
  const float* grid     = (const float*)d_in[1];
  const float* anc      = (const float*)d_in[2];
  const float* bboxes   = (const float*)d_in[3];
  const int*   pos_idx  = (const int*)d_in[4];
  const int*   neg_idx  = (const int*)d_in[5];
  const float* W1       = (const float*)d_in[6];
  const float* b1       = (const float*)d_in[7];
  const float* W2       = (const float*)d_in[8];
  const float* b2       = (const float*)d_in[9];
  float* out = (float*)d_out;

  // ws: W1f (bf16 frag-order, 327680 B) then Part (KSPLIT * B*HW*HID fp32)
  uint4* W1f = (uint4*)d_ws;
  float* Part = (float*)((char*)d_ws + 327680);

  hipLaunchKernelGGL(prep_w1, dim3(80), dim3(256), 0, stream, W1, W1f);
  hipLaunchKernelGGL(gemm1_mfma, dim3(13, B_SZ, KSPLIT), dim3(256), 0, stream,
                     features, (const unsigned short*)W1f, Part);
  hipLaunchKernelGGL(iou_kernel, dim3((P_NUM + IOU_PB - 1) / IOU_PB, B_SZ),
                     dim3(256), 0, stream, grid, anc, bboxes, out + IOU_OFF);
  hipLaunchKernelGGL(gather_kernel, dim3(2 * M_IDX / 4), dim3(256),
                     0, stream, pos_idx, neg_idx, Part, b1, W2, b2, out);
}